// Round 1
// baseline (536.100 us; speedup 1.0000x reference)
//
#include <hip/hip_runtime.h>
#include <math.h>

// Problem constants (fixed by the reference file)
constexpr int G    = 256;   // N_GRAPHS
constexpr int EMB  = 64;
constexpr int ERBF = 16;

// ---------------------------------------------------------------------------
// Kernel 1: fold W2, W_out, W_rbf into M[64][16]:
//   M[p][k] = sum_j W2[p][j] * W_out[j] * W_rbf[k][j]
// so that score_e = silu(e @ W1) @ M @ rbf_e
// ---------------------------------------------------------------------------
__global__ void prep_M_kernel(const float* __restrict__ W2,
                              const float* __restrict__ W_rbf,
                              const float* __restrict__ W_out,
                              float* __restrict__ M) {
    int t = blockIdx.x * blockDim.x + threadIdx.x;
    if (t >= EMB * ERBF) return;
    int p = t >> 4;      // 0..63
    int k = t & 15;      // 0..15
    float acc = 0.f;
    for (int j = 0; j < EMB; ++j)
        acc = fmaf(W2[p * EMB + j] * W_out[j], W_rbf[k * EMB + j], acc);
    M[p * ERBF + k] = acc;
}

// ---------------------------------------------------------------------------
// Kernel 2: per-edge score + symmetric outer accumulation into per-block
// partial sums (6 unique sym entries + edge count per graph).
//   score_e = silu(e @ W1) @ M @ rbf_e
//   contribution = score_e * d d^T / ||d||   (0.5*(outer+outer^T) simplifies)
// Division by per-graph edge count is deferred to the reduce kernel (linear).
// W1/M reads are wave-uniform -> scalar loads (SGPR-operand v_fmac).
// ---------------------------------------------------------------------------
__global__ __launch_bounds__(256) void edge_kernel(
    const float* __restrict__ edge_emb,   // [ne][64]
    const int*   __restrict__ edge_src,   // row 0 of edge_index, [ne]
    const float* __restrict__ dvec,       // [ne][3]
    const int*   __restrict__ batch,      // [n_nodes]
    const float* __restrict__ rbf,        // [ne][16]
    const float* __restrict__ W1,         // [64][64]
    const float* __restrict__ M,          // [64][16]
    float* __restrict__ partial,          // [nblk][G*8]
    int ne, int nblk)
{
    __shared__ float acc[G * 8];          // 6 sym + count + pad, per graph
    for (int i = threadIdx.x; i < G * 8; i += 256) acc[i] = 0.f;
    __syncthreads();

    for (int e = blockIdx.x * 256 + threadIdx.x; e < ne; e += nblk * 256) {
        // ---- h = e @ W1 (fp32, W1 via scalar loads) ----
        float h[EMB];
#pragma unroll
        for (int j = 0; j < EMB; ++j) h[j] = 0.f;

        const float4* ep = (const float4*)(edge_emb + (size_t)e * EMB);
        for (int k4 = 0; k4 < EMB / 4; ++k4) {
            float4 ev = ep[k4];
            const float* w0 = W1 + (k4 * 4) * EMB;
#pragma unroll
            for (int j = 0; j < EMB; ++j) h[j] = fmaf(ev.x, w0[j], h[j]);
#pragma unroll
            for (int j = 0; j < EMB; ++j) h[j] = fmaf(ev.y, w0[EMB + j], h[j]);
#pragma unroll
            for (int j = 0; j < EMB; ++j) h[j] = fmaf(ev.z, w0[2 * EMB + j], h[j]);
#pragma unroll
            for (int j = 0; j < EMB; ++j) h[j] = fmaf(ev.w, w0[3 * EMB + j], h[j]);
        }

        // ---- silu ----
#pragma unroll
        for (int j = 0; j < EMB; ++j) h[j] = h[j] / (1.f + __expf(-h[j]));

        // ---- t = h @ M (M via scalar loads) ----
        float t[ERBF];
#pragma unroll
        for (int k = 0; k < ERBF; ++k) t[k] = 0.f;
#pragma unroll
        for (int p = 0; p < EMB; ++p) {
#pragma unroll
            for (int k = 0; k < ERBF; ++k)
                t[k] = fmaf(h[p], M[p * ERBF + k], t[k]);
        }

        // ---- score = t . rbf_e ----
        const float4* rp = (const float4*)(rbf + (size_t)e * ERBF);
        float score = 0.f;
#pragma unroll
        for (int q = 0; q < 4; ++q) {
            float4 rv = rp[q];
            score = fmaf(t[4 * q + 0], rv.x, score);
            score = fmaf(t[4 * q + 1], rv.y, score);
            score = fmaf(t[4 * q + 2], rv.z, score);
            score = fmaf(t[4 * q + 3], rv.w, score);
        }

        // ---- geometry + scatter ----
        int src = edge_src[e];
        int g   = batch[src];
        size_t de = (size_t)e * 3;
        float dx = dvec[de], dy = dvec[de + 1], dz = dvec[de + 2];
        float nrm = sqrtf(dx * dx + dy * dy + dz * dz);
        float c = score / nrm;

        float* a = &acc[g * 8];
        atomicAdd(a + 0, c * dx * dx);
        atomicAdd(a + 1, c * dx * dy);
        atomicAdd(a + 2, c * dx * dz);
        atomicAdd(a + 3, c * dy * dy);
        atomicAdd(a + 4, c * dy * dz);
        atomicAdd(a + 5, c * dz * dz);
        atomicAdd(a + 6, 1.0f);
    }

    __syncthreads();
    float* outp = partial + (size_t)blockIdx.x * (G * 8);
    for (int i = threadIdx.x; i < G * 8; i += 256) outp[i] = acc[i];
}

// ---------------------------------------------------------------------------
// Kernel 3: reduce per-block partials, divide by count, mirror to 3x3.
// One block per graph.
// ---------------------------------------------------------------------------
__global__ __launch_bounds__(256) void reduce_kernel(
    const float* __restrict__ partial, float* __restrict__ out, int nblk)
{
    int g = blockIdx.x;
    __shared__ float red[256][8];
    float loc[8];
#pragma unroll
    for (int c = 0; c < 8; ++c) loc[c] = 0.f;

    for (int b = threadIdx.x; b < nblk; b += 256) {
        const float4* p = (const float4*)(partial + (size_t)b * (G * 8) + g * 8);
        float4 v0 = p[0], v1 = p[1];
        loc[0] += v0.x; loc[1] += v0.y; loc[2] += v0.z; loc[3] += v0.w;
        loc[4] += v1.x; loc[5] += v1.y; loc[6] += v1.z; loc[7] += v1.w;
    }
#pragma unroll
    for (int c = 0; c < 8; ++c) red[threadIdx.x][c] = loc[c];
    __syncthreads();

    for (int off = 128; off >= 1; off >>= 1) {
        if (threadIdx.x < off) {
#pragma unroll
            for (int c = 0; c < 8; ++c)
                red[threadIdx.x][c] += red[threadIdx.x + off][c];
        }
        __syncthreads();
    }

    if (threadIdx.x == 0) {
        float cnt = red[0][6];
        float inv = (cnt > 0.f) ? (1.f / cnt) : 0.f;
        float xx = red[0][0] * inv, xy = red[0][1] * inv, xz = red[0][2] * inv;
        float yy = red[0][3] * inv, yz = red[0][4] * inv, zz = red[0][5] * inv;
        float* o = out + g * 9;
        o[0] = xx; o[1] = xy; o[2] = xz;
        o[3] = xy; o[4] = yy; o[5] = yz;
        o[6] = xz; o[7] = yz; o[8] = zz;
    }
}

// ---------------------------------------------------------------------------
extern "C" void kernel_launch(void* const* d_in, const int* in_sizes, int n_in,
                              void* d_out, int out_size, void* d_ws, size_t ws_size,
                              hipStream_t stream) {
    const float* edge_emb   = (const float*)d_in[0];
    const int*   edge_index = (const int*)  d_in[1];  // [2][ne], row 0 = src
    const float* dvec       = (const float*)d_in[2];
    // d_in[3] lattice: unused by the reference computation
    const int*   batch      = (const int*)  d_in[4];
    const float* rbf        = (const float*)d_in[5];
    // const float* W1 below
    const float* W1         = (const float*)d_in[6];
    const float* W2         = (const float*)d_in[7];
    const float* W_rbf      = (const float*)d_in[8];
    const float* W_out      = (const float*)d_in[9];
    float* out = (float*)d_out;

    int ne = in_sizes[0] / EMB;

    // ws layout: [0, 4096): M (64x16 floats). [4096, ...): per-block partials.
    float* M = (float*)d_ws;
    float* partial = (float*)((char*)d_ws + 4096);
    size_t avail = (ws_size > 4096) ? (ws_size - 4096) : 0;
    int nblk = (int)(avail / (G * 8 * sizeof(float)));
    if (nblk > 1024) nblk = 1024;   // 4 blocks/CU at 256 threads
    if (nblk < 1)    nblk = 1;

    prep_M_kernel<<<4, 256, 0, stream>>>(W2, W_rbf, W_out, M);
    edge_kernel<<<nblk, 256, 0, stream>>>(edge_emb, edge_index, dvec, batch,
                                          rbf, W1, M, partial, ne, nblk);
    reduce_kernel<<<G, 256, 0, stream>>>(partial, out, nblk);
}

// Round 2
// 428.457 us; speedup vs baseline: 1.2512x; 1.2512x over previous
//
#include <hip/hip_runtime.h>
#include <math.h>

// Problem constants (fixed by the reference file)
constexpr int G    = 256;   // N_GRAPHS
constexpr int EMB  = 64;
constexpr int ERBF = 16;

typedef __attribute__((ext_vector_type(8))) short bf16x8;
typedef __attribute__((ext_vector_type(4))) float f32x4;

// fp32 -> bf16 (round-to-nearest-even), bit-level
static __device__ __forceinline__ short bf16_rne(float f) {
    union { float f; unsigned u; } v; v.f = f;
    unsigned r = (v.u + 0x7FFFu + ((v.u >> 16) & 1u)) >> 16;
    return (short)r;
}

// ---------------------------------------------------------------------------
// Kernel 1: fold W2, W_out, W_rbf into M[64][16]:
//   M[p][k] = sum_j W2[p][j] * W_out[j] * W_rbf[k][j]
// so that score_e = silu(e @ W1) @ M @ rbf_e
// ---------------------------------------------------------------------------
__global__ void prep_M_kernel(const float* __restrict__ W2,
                              const float* __restrict__ W_rbf,
                              const float* __restrict__ W_out,
                              float* __restrict__ M) {
    int t = blockIdx.x * blockDim.x + threadIdx.x;
    if (t >= EMB * ERBF) return;
    int p = t >> 4;
    int k = t & 15;
    float acc = 0.f;
    for (int j = 0; j < EMB; ++j)
        acc = fmaf(W2[p * EMB + j] * W_out[j], W_rbf[k * EMB + j], acc);
    M[p * ERBF + k] = acc;
}

// ---------------------------------------------------------------------------
// Kernel 2 (MFMA): per wave, tiles of 16 edges.
//   H[16x64]  = E_tile @ W1      (4 N-tiles x 2 K-chunks = 8 mfma)
//   T[16x16]  = silu(H) @ M      (2 mfma, silu(H) transposed through LDS)
//   score_e   = sum_k T[e][k] * rbf[e][k]   (shfl_xor butterfly over 16 cols)
//   scatter   = score/|d| * d d^T  into per-graph LDS bins (stride 9: coprime
//               with 32 banks; batch_edge is RANDOM, stride 8 -> 4-bank alias)
// W1/M fragments live in registers for the whole kernel (~48 VGPRs).
// A-fragments are loaded straight from global: lane(m=edge,q) reads the 32B
// k-slice [c*32+q*8, +8) of its edge row -> all bytes of the 4KB tile are
// consumed across the 4 dwordx4 loads, zero over-fetch.
// ---------------------------------------------------------------------------
__global__ __launch_bounds__(256, 4) void edge_kernel(
    const float* __restrict__ edge_emb,   // [ne][64]
    const int*   __restrict__ edge_src,   // row 0 of edge_index, [ne]
    const float* __restrict__ dvec,       // [ne][3]
    const int*   __restrict__ batch,      // [n_nodes]
    const float* __restrict__ rbf,        // [ne][16]
    const float* __restrict__ W1,         // [64][64]
    const float* __restrict__ M,          // [64][16]
    float* __restrict__ partial,          // [nblk][G*8]
    int ne, int nblk)
{
    constexpr int HSTRIDE = 72;           // bf16 row stride: 16B-aligned, breaks
                                          // the 16-way b128 read conflict (->2-way, free)
    __shared__ short hT[4][16 * HSTRIDE]; // per-wave silu(H) transpose buffer
    __shared__ float accs[G * 9];         // 6 sym + count, stride 9 (bank spread)

    const int tid  = threadIdx.x;
    const int w    = tid >> 6;
    const int lane = tid & 63;
    const int q    = lane >> 4;   // quad 0..3
    const int col  = lane & 15;   // n / m index

    for (int i = tid; i < G * 9; i += 256) accs[i] = 0.f;

    // ---- one-time: W1 and M fragments into registers (B-operand layout:
    //      lane holds B[k = c*32 + q*8 + j][n = nt*16 + col]) ----
    bf16x8 w1f[4][2];
#pragma unroll
    for (int nt = 0; nt < 4; ++nt)
#pragma unroll
        for (int c = 0; c < 2; ++c) {
            bf16x8 wv;
#pragma unroll
            for (int j = 0; j < 8; ++j)
                wv[j] = bf16_rne(W1[(c * 32 + q * 8 + j) * EMB + nt * 16 + col]);
            w1f[nt][c] = wv;
        }
    bf16x8 mf[2];
#pragma unroll
    for (int c = 0; c < 2; ++c) {
        bf16x8 mv;
#pragma unroll
        for (int j = 0; j < 8; ++j)
            mv[j] = bf16_rne(M[(c * 32 + q * 8 + j) * ERBF + col]);
        mf[c] = mv;
    }
    __syncthreads();   // accs zeroed before any atomics

    const long tiles_step = (long)nblk * 64;
    for (long tbase = (long)blockIdx.x * 64; tbase < ne; tbase += tiles_step) {
        const long e0 = tbase + (long)w * 16;   // this wave's 16 edges

        // ---- A fragments straight from global (bf16 convert in-reg) ----
        bf16x8 af[2];
        const long erow = e0 + col;             // lane's edge row (m index)
        const bool rowok = (erow < ne);
#pragma unroll
        for (int c = 0; c < 2; ++c) {
            bf16x8 a;
            if (rowok) {
                const float4* p = (const float4*)(edge_emb + (size_t)erow * EMB + c * 32 + q * 8);
                float4 v0 = p[0], v1 = p[1];
                a[0] = bf16_rne(v0.x); a[1] = bf16_rne(v0.y);
                a[2] = bf16_rne(v0.z); a[3] = bf16_rne(v0.w);
                a[4] = bf16_rne(v1.x); a[5] = bf16_rne(v1.y);
                a[6] = bf16_rne(v1.z); a[7] = bf16_rne(v1.w);
            } else {
#pragma unroll
                for (int j = 0; j < 8; ++j) a[j] = 0;
            }
            af[c] = a;
        }

        // ---- H = E @ W1 ----
        f32x4 hacc[4];
#pragma unroll
        for (int nt = 0; nt < 4; ++nt) {
            f32x4 z = {0.f, 0.f, 0.f, 0.f};
            z = __builtin_amdgcn_mfma_f32_16x16x32_bf16(af[0], w1f[nt][0], z, 0, 0, 0);
            z = __builtin_amdgcn_mfma_f32_16x16x32_bf16(af[1], w1f[nt][1], z, 0, 0, 0);
            hacc[nt] = z;
        }

        // ---- silu + write to LDS in [edge][feat] order (bf16) ----
        // C-layout: hacc[nt][r] = H[edge = q*4+r][feat = nt*16+col]
#pragma unroll
        for (int nt = 0; nt < 4; ++nt)
#pragma unroll
            for (int r = 0; r < 4; ++r) {
                float x = hacc[nt][r];
                float s = x * __builtin_amdgcn_rcpf(1.f + __expf(-x));
                hT[w][(q * 4 + r) * HSTRIDE + nt * 16 + col] = bf16_rne(s);
            }
        __syncthreads();   // cross-lane LDS visibility (per-wave buffer, but
                           // barrier guarantees the waitcnt; uniform across block)

        // ---- A2 = silu(H) in A-operand layout, T = A2 @ M ----
        f32x4 tacc = {0.f, 0.f, 0.f, 0.f};
#pragma unroll
        for (int c = 0; c < 2; ++c) {
            const bf16x8* ap = (const bf16x8*)&hT[w][col * HSTRIDE + c * 32 + q * 8];
            tacc = __builtin_amdgcn_mfma_f32_16x16x32_bf16(*ap, mf[c], tacc, 0, 0, 0);
        }

        // ---- score: dot T row with rbf row, butterfly over the 16 cols ----
        float sc[4];
#pragma unroll
        for (int r = 0; r < 4; ++r) {
            long e = e0 + q * 4 + r;
            float rv = (e < ne) ? rbf[(size_t)e * ERBF + col] : 0.f;
            sc[r] = tacc[r] * rv;
        }
#pragma unroll
        for (int m = 1; m < 16; m <<= 1) {
#pragma unroll
            for (int r = 0; r < 4; ++r) sc[r] += __shfl_xor(sc[r], m);
        }

        // ---- geometry + scatter: lane with col<4 owns edge q*4+col ----
        if (col < 4) {
            long e = e0 + q * 4 + col;
            if (e < ne) {
                float s = sc[col];
                int   g = batch[edge_src[e]];
                size_t de = (size_t)e * 3;
                float dx = dvec[de], dy = dvec[de + 1], dz = dvec[de + 2];
                float nrm = sqrtf(dx * dx + dy * dy + dz * dz);
                float cc = s / nrm;
                float* a = &accs[g * 9];
                atomicAdd(a + 0, cc * dx * dx);
                atomicAdd(a + 1, cc * dx * dy);
                atomicAdd(a + 2, cc * dx * dz);
                atomicAdd(a + 3, cc * dy * dy);
                atomicAdd(a + 4, cc * dy * dz);
                atomicAdd(a + 5, cc * dz * dz);
                atomicAdd(a + 6, 1.0f);
            }
        }
        __syncthreads();   // hT reuse next iteration + accs ordering
    }

    // ---- flush per-block bins (stride 9 -> stride 8 for the reducer) ----
    float* outp = partial + (size_t)blockIdx.x * (G * 8);
    {
        int g = tid;  // 256 threads == 256 graphs
        float* a = &accs[g * 9];
        float4 p0 = {a[0], a[1], a[2], a[3]};
        float4 p1 = {a[4], a[5], a[6], 0.f};
        ((float4*)(outp + g * 8))[0] = p0;
        ((float4*)(outp + g * 8))[1] = p1;
    }
}

// ---------------------------------------------------------------------------
// Kernel 3: reduce per-block partials, divide by count, mirror to 3x3.
// ---------------------------------------------------------------------------
__global__ __launch_bounds__(256) void reduce_kernel(
    const float* __restrict__ partial, float* __restrict__ out, int nblk)
{
    int g = blockIdx.x;
    __shared__ float red[256][8];
    float loc[8];
#pragma unroll
    for (int c = 0; c < 8; ++c) loc[c] = 0.f;

    for (int b = threadIdx.x; b < nblk; b += 256) {
        const float4* p = (const float4*)(partial + (size_t)b * (G * 8) + g * 8);
        float4 v0 = p[0], v1 = p[1];
        loc[0] += v0.x; loc[1] += v0.y; loc[2] += v0.z; loc[3] += v0.w;
        loc[4] += v1.x; loc[5] += v1.y; loc[6] += v1.z; loc[7] += v1.w;
    }
#pragma unroll
    for (int c = 0; c < 8; ++c) red[threadIdx.x][c] = loc[c];
    __syncthreads();

    for (int off = 128; off >= 1; off >>= 1) {
        if (threadIdx.x < off) {
#pragma unroll
            for (int c = 0; c < 8; ++c)
                red[threadIdx.x][c] += red[threadIdx.x + off][c];
        }
        __syncthreads();
    }

    if (threadIdx.x == 0) {
        float cnt = red[0][6];
        float inv = (cnt > 0.f) ? (1.f / cnt) : 0.f;
        float xx = red[0][0] * inv, xy = red[0][1] * inv, xz = red[0][2] * inv;
        float yy = red[0][3] * inv, yz = red[0][4] * inv, zz = red[0][5] * inv;
        float* o = out + g * 9;
        o[0] = xx; o[1] = xy; o[2] = xz;
        o[3] = xy; o[4] = yy; o[5] = yz;
        o[6] = xz; o[7] = yz; o[8] = zz;
    }
}

// ---------------------------------------------------------------------------
extern "C" void kernel_launch(void* const* d_in, const int* in_sizes, int n_in,
                              void* d_out, int out_size, void* d_ws, size_t ws_size,
                              hipStream_t stream) {
    const float* edge_emb   = (const float*)d_in[0];
    const int*   edge_index = (const int*)  d_in[1];  // [2][ne], row 0 = src
    const float* dvec       = (const float*)d_in[2];
    // d_in[3] lattice: unused by the reference computation
    const int*   batch      = (const int*)  d_in[4];
    const float* rbf        = (const float*)d_in[5];
    const float* W1         = (const float*)d_in[6];
    const float* W2         = (const float*)d_in[7];
    const float* W_rbf      = (const float*)d_in[8];
    const float* W_out      = (const float*)d_in[9];
    float* out = (float*)d_out;

    int ne = in_sizes[0] / EMB;

    // ws layout: [0, 4096): M (64x16). [4096, ...): per-block partials (G*8 fl).
    float* M = (float*)d_ws;
    float* partial = (float*)((char*)d_ws + 4096);
    size_t avail = (ws_size > 4096) ? (ws_size - 4096) : 0;
    int nblk = (int)(avail / (G * 8 * sizeof(float)));
    int tiles = (ne + 63) / 64;
    if (nblk > 1024)  nblk = 1024;   // 4 blocks/CU at 256 thr, 128 VGPR
    if (nblk > tiles) nblk = tiles;
    if (nblk < 1)     nblk = 1;

    prep_M_kernel<<<4, 256, 0, stream>>>(W2, W_rbf, W_out, M);
    edge_kernel<<<nblk, 256, 0, stream>>>(edge_emb, edge_index, dvec, batch,
                                          rbf, W1, M, partial, ne, nblk);
    reduce_kernel<<<G, 256, 0, stream>>>(partial, out, nblk);
}

// Round 3
// 426.838 us; speedup vs baseline: 1.2560x; 1.0038x over previous
//
#include <hip/hip_runtime.h>
#include <math.h>

// Problem constants (fixed by the reference file)
constexpr int G    = 256;   // N_GRAPHS
constexpr int EMB  = 64;
constexpr int ERBF = 16;

typedef __attribute__((ext_vector_type(8))) short bf16x8;
typedef __attribute__((ext_vector_type(4))) float f32x4;

// fp32 -> bf16 (round-to-nearest-even), bit-level
static __device__ __forceinline__ short bf16_rne(float f) {
    union { float f; unsigned u; } v; v.f = f;
    unsigned r = (v.u + 0x7FFFu + ((v.u >> 16) & 1u)) >> 16;
    return (short)r;
}

// ---------------------------------------------------------------------------
// Kernel 1: fold W2, W_out, W_rbf into M[64][16]:
//   M[p][k] = sum_j W2[p][j] * W_out[j] * W_rbf[k][j]
// so that score_e = silu(e @ W1) @ M @ rbf_e
// ---------------------------------------------------------------------------
__global__ void prep_M_kernel(const float* __restrict__ W2,
                              const float* __restrict__ W_rbf,
                              const float* __restrict__ W_out,
                              float* __restrict__ M) {
    int t = blockIdx.x * blockDim.x + threadIdx.x;
    if (t >= EMB * ERBF) return;
    int p = t >> 4;
    int k = t & 15;
    float acc = 0.f;
    for (int j = 0; j < EMB; ++j)
        acc = fmaf(W2[p * EMB + j] * W_out[j], W_rbf[k * EMB + j], acc);
    M[p * ERBF + k] = acc;
}

// ---------------------------------------------------------------------------
// Kernel 2 (MFMA, barrier-free loop): per wave, independent tiles of 16 edges.
//   H[16x64] = E_tile @ W1                       (8 mfma, C-layout)
//   V[16x64] = rbf_tile(pad K->32) @ M^T         (4 mfma, SAME C-layout)
//   score_e  = sum_p silu(H[e][p]) * V[e][p]     (in-lane dot over nt,
//                                                 shfl_xor butterfly over col)
//   scatter  = score/|d| * d d^T  into per-graph LDS bins (stride 9, coprime
//              with 32 banks; batch_edge is random -> stride 8 would 4-bank-alias)
// Restructuring rationale: V lands in the same C-layout as H, so the old
// LDS transpose of silu(H) into A-layout (and BOTH per-iteration barriers)
// disappears. Waves are fully decoupled -> HBM latency is hidden by TLP.
// W1/M^T fragments live in registers for the whole kernel (~48 VGPRs).
// ---------------------------------------------------------------------------
__global__ __launch_bounds__(256, 4) void edge_kernel(
    const float* __restrict__ edge_emb,   // [ne][64]
    const int*   __restrict__ edge_src,   // row 0 of edge_index, [ne]
    const float* __restrict__ dvec,       // [ne][3]
    const int*   __restrict__ batch,      // [n_nodes]
    const float* __restrict__ rbf,        // [ne][16]
    const float* __restrict__ W1,         // [64][64]
    const float* __restrict__ M,          // [64][16]
    float* __restrict__ partial,          // [nblk][G*8]
    int ne, int nblk)
{
    __shared__ float accs[G * 9];         // 6 sym + count, stride 9 (bank spread)

    const int tid  = threadIdx.x;
    const int w    = tid >> 6;
    const int lane = tid & 63;
    const int q    = lane >> 4;   // quad 0..3 (k-chunk selector)
    const int col  = lane & 15;   // m / n index

    for (int i = tid; i < G * 9; i += 256) accs[i] = 0.f;

    // ---- one-time: W1 fragments (B-layout: lane holds B[k=c*32+q*8+j][n]) ----
    bf16x8 w1f[4][2];
#pragma unroll
    for (int nt = 0; nt < 4; ++nt)
#pragma unroll
        for (int c = 0; c < 2; ++c) {
            bf16x8 wv;
#pragma unroll
            for (int j = 0; j < 8; ++j)
                wv[j] = bf16_rne(W1[(c * 32 + q * 8 + j) * EMB + nt * 16 + col]);
            w1f[nt][c] = wv;
        }
    // ---- M^T fragments for V = rbf @ M^T:  B[k][p] = M[p][k], k>=16 -> 0 ----
    bf16x8 mtf[4];
#pragma unroll
    for (int nt = 0; nt < 4; ++nt) {
        bf16x8 mv;
#pragma unroll
        for (int j = 0; j < 8; ++j) {
            int k = q * 8 + j;
            mv[j] = (k < ERBF) ? bf16_rne(M[(nt * 16 + col) * ERBF + k]) : (short)0;
        }
        mtf[nt] = mv;
    }
    __syncthreads();   // accs zeroed before any atomics

    const long estep = (long)nblk * 4 * 16;   // edges per grid iteration
    for (long e0 = ((long)blockIdx.x * 4 + w) * 16; e0 < ne; e0 += estep) {
        const long erow  = e0 + col;          // this lane's edge row (m index)
        const bool rowok = (erow < ne);

        // ---- A fragments straight from global (bf16 convert in-reg) ----
        bf16x8 af[2];
#pragma unroll
        for (int c = 0; c < 2; ++c) {
            bf16x8 a;
            if (rowok) {
                const float4* p = (const float4*)(edge_emb + (size_t)erow * EMB + c * 32 + q * 8);
                float4 v0 = p[0], v1 = p[1];
                a[0] = bf16_rne(v0.x); a[1] = bf16_rne(v0.y);
                a[2] = bf16_rne(v0.z); a[3] = bf16_rne(v0.w);
                a[4] = bf16_rne(v1.x); a[5] = bf16_rne(v1.y);
                a[6] = bf16_rne(v1.z); a[7] = bf16_rne(v1.w);
            } else {
#pragma unroll
                for (int j = 0; j < 8; ++j) a[j] = 0;
            }
            af[c] = a;
        }
        // ---- rbf A-fragment (K padded 16->32: quads 2,3 are zero) ----
        bf16x8 rf;
        if (q < 2 && rowok) {
            const float4* p = (const float4*)(rbf + (size_t)erow * ERBF + q * 8);
            float4 v0 = p[0], v1 = p[1];
            rf[0] = bf16_rne(v0.x); rf[1] = bf16_rne(v0.y);
            rf[2] = bf16_rne(v0.z); rf[3] = bf16_rne(v0.w);
            rf[4] = bf16_rne(v1.x); rf[5] = bf16_rne(v1.y);
            rf[6] = bf16_rne(v1.z); rf[7] = bf16_rne(v1.w);
        } else {
#pragma unroll
            for (int j = 0; j < 8; ++j) rf[j] = 0;
        }

        // ---- H = E @ W1 ;  V = rbf @ M^T  (independent MFMA chains) ----
        f32x4 hacc[4], vacc[4];
#pragma unroll
        for (int nt = 0; nt < 4; ++nt) {
            f32x4 z = {0.f, 0.f, 0.f, 0.f};
            z = __builtin_amdgcn_mfma_f32_16x16x32_bf16(af[0], w1f[nt][0], z, 0, 0, 0);
            z = __builtin_amdgcn_mfma_f32_16x16x32_bf16(af[1], w1f[nt][1], z, 0, 0, 0);
            hacc[nt] = z;
            f32x4 zv = {0.f, 0.f, 0.f, 0.f};
            vacc[nt] = __builtin_amdgcn_mfma_f32_16x16x32_bf16(rf, mtf[nt], zv, 0, 0, 0);
        }

        // ---- score partials: lane(q,col) holds (e=q*4+r, p=nt*16+col) ----
        float sc[4];
#pragma unroll
        for (int r = 0; r < 4; ++r) {
            float acc = 0.f;
#pragma unroll
            for (int nt = 0; nt < 4; ++nt) {
                float x = hacc[nt][r];
                float s = x * __builtin_amdgcn_rcpf(1.f + __expf(-x));
                acc = fmaf(s, vacc[nt][r], acc);
            }
            sc[r] = acc;
        }
#pragma unroll
        for (int m = 1; m < 16; m <<= 1) {
#pragma unroll
            for (int r = 0; r < 4; ++r) sc[r] += __shfl_xor(sc[r], m);
        }

        // ---- geometry + scatter: lane with col<4 owns edge q*4+col ----
        if (col < 4) {
            long e = e0 + q * 4 + col;
            if (e < ne) {
                float s = sc[col];
                int   g = batch[edge_src[e]];
                size_t de = (size_t)e * 3;
                float dx = dvec[de], dy = dvec[de + 1], dz = dvec[de + 2];
                float nrm = sqrtf(dx * dx + dy * dy + dz * dz);
                float cc = s / nrm;
                float* a = &accs[g * 9];
                atomicAdd(a + 0, cc * dx * dx);
                atomicAdd(a + 1, cc * dx * dy);
                atomicAdd(a + 2, cc * dx * dz);
                atomicAdd(a + 3, cc * dy * dy);
                atomicAdd(a + 4, cc * dy * dz);
                atomicAdd(a + 5, cc * dz * dz);
                atomicAdd(a + 6, 1.0f);
            }
        }
        // no barrier: waves are fully independent until the final flush
    }

    __syncthreads();
    // ---- flush per-block bins (stride 9 -> stride 8 for the reducer) ----
    float* outp = partial + (size_t)blockIdx.x * (G * 8);
    {
        int g = tid;  // 256 threads == 256 graphs
        float* a = &accs[g * 9];
        float4 p0 = {a[0], a[1], a[2], a[3]};
        float4 p1 = {a[4], a[5], a[6], 0.f};
        ((float4*)(outp + g * 8))[0] = p0;
        ((float4*)(outp + g * 8))[1] = p1;
    }
}

// ---------------------------------------------------------------------------
// Kernel 3: reduce per-block partials, divide by count, mirror to 3x3.
// ---------------------------------------------------------------------------
__global__ __launch_bounds__(256) void reduce_kernel(
    const float* __restrict__ partial, float* __restrict__ out, int nblk)
{
    int g = blockIdx.x;
    __shared__ float red[256][8];
    float loc[8];
#pragma unroll
    for (int c = 0; c < 8; ++c) loc[c] = 0.f;

    for (int b = threadIdx.x; b < nblk; b += 256) {
        const float4* p = (const float4*)(partial + (size_t)b * (G * 8) + g * 8);
        float4 v0 = p[0], v1 = p[1];
        loc[0] += v0.x; loc[1] += v0.y; loc[2] += v0.z; loc[3] += v0.w;
        loc[4] += v1.x; loc[5] += v1.y; loc[6] += v1.z; loc[7] += v1.w;
    }
#pragma unroll
    for (int c = 0; c < 8; ++c) red[threadIdx.x][c] = loc[c];
    __syncthreads();

    for (int off = 128; off >= 1; off >>= 1) {
        if (threadIdx.x < off) {
#pragma unroll
            for (int c = 0; c < 8; ++c)
                red[threadIdx.x][c] += red[threadIdx.x + off][c];
        }
        __syncthreads();
    }

    if (threadIdx.x == 0) {
        float cnt = red[0][6];
        float inv = (cnt > 0.f) ? (1.f / cnt) : 0.f;
        float xx = red[0][0] * inv, xy = red[0][1] * inv, xz = red[0][2] * inv;
        float yy = red[0][3] * inv, yz = red[0][4] * inv, zz = red[0][5] * inv;
        float* o = out + g * 9;
        o[0] = xx; o[1] = xy; o[2] = xz;
        o[3] = xy; o[4] = yy; o[5] = yz;
        o[6] = xz; o[7] = yz; o[8] = zz;
    }
}

// ---------------------------------------------------------------------------
extern "C" void kernel_launch(void* const* d_in, const int* in_sizes, int n_in,
                              void* d_out, int out_size, void* d_ws, size_t ws_size,
                              hipStream_t stream) {
    const float* edge_emb   = (const float*)d_in[0];
    const int*   edge_index = (const int*)  d_in[1];  // [2][ne], row 0 = src
    const float* dvec       = (const float*)d_in[2];
    // d_in[3] lattice: unused by the reference computation
    const int*   batch      = (const int*)  d_in[4];
    const float* rbf        = (const float*)d_in[5];
    const float* W1         = (const float*)d_in[6];
    const float* W2         = (const float*)d_in[7];
    const float* W_rbf      = (const float*)d_in[8];
    const float* W_out      = (const float*)d_in[9];
    float* out = (float*)d_out;

    int ne = in_sizes[0] / EMB;

    // ws layout: [0, 4096): M (64x16). [4096, ...): per-block partials (G*8 fl).
    float* M = (float*)d_ws;
    float* partial = (float*)((char*)d_ws + 4096);
    size_t avail = (ws_size > 4096) ? (ws_size - 4096) : 0;
    int nblk = (int)(avail / (G * 8 * sizeof(float)));
    int tiles = (ne + 63) / 64;
    if (nblk > 1024)  nblk = 1024;   // 4 blocks/CU at 256 thr, <=128 VGPR
    if (nblk > tiles) nblk = tiles;
    if (nblk < 1)     nblk = 1;

    prep_M_kernel<<<4, 256, 0, stream>>>(W2, W_rbf, W_out, M);
    edge_kernel<<<nblk, 256, 0, stream>>>(edge_emb, edge_index, dvec, batch,
                                          rbf, W1, M, partial, ne, nblk);
    reduce_kernel<<<G, 256, 0, stream>>>(partial, out, nblk);
}